// Round 7
// baseline (1060.246 us; speedup 1.0000x reference)
//
#include <hip/hip_runtime.h>
#include <hip/hip_bf16.h>

#define T_LEN 256
#define B_SZ  256
#define EMB   128
#define UNITS 100
#define GATES 400           // 4*UNITS
#define NCOL  800           // xw2 cols: [fwd 400 | bwd 400], each unit*4+gate
#define CPAD  512           // padded MFMA col-space per dir: 128 units x 4 gates
#define HROW  136           // h-plane row stride (f16 elems), 16B-aligned rows
#define NTILE 4             // 32 tiles / 8 waves

typedef __attribute__((ext_vector_type(8))) short short8v;
typedef __attribute__((ext_vector_type(4))) short short4v;
typedef __attribute__((ext_vector_type(4))) float f32x4;
typedef __attribute__((ext_vector_type(8))) _Float16 half8;
typedef __attribute__((ext_vector_type(4))) _Float16 half4;

static __device__ __forceinline__ float bf2f(short s) {
    unsigned u = ((unsigned)(unsigned short)s) << 16;
    return __builtin_bit_cast(float, u);
}
static __device__ __forceinline__ short f2bf(float f) {
    return __builtin_bit_cast(short, __float2bfloat16(f));
}
static __device__ __forceinline__ float fast_sigmoid(float x) {
    return 1.f / (1.f + __expf(-x));
}
static __device__ __forceinline__ float fast_tanh(float x) {
    return 1.f - 2.f / (1.f + __expf(2.f * x));
}

// ---------------------------------------------------------------------------
// prep: (a) WbT bf16 transposed word-part weights  (b) P_pos/P_dep tables
//       (c) MFMA lane-layout probes: flag[0]=bf16, flag[1]=f16
// ---------------------------------------------------------------------------
#define PREP_WT_BLOCKS 100
#define PREP_TAB_BLOCKS 107

__global__ __launch_bounds__(256) void prep(
    const float* __restrict__ Wf, const float* __restrict__ Wb,
    const float* __restrict__ bf_, const float* __restrict__ bb_,
    const float* __restrict__ Ep, const float* __restrict__ Ed,
    __hip_bfloat16* __restrict__ WbT, float* __restrict__ Ppos,
    float* __restrict__ Pdep, int* __restrict__ flag)
{
    __shared__ short Ap[16 * 32];
    __shared__ short Bp[32 * 16];

    const int bx = blockIdx.x, tid = threadIdx.x;

    if (bx < PREP_WT_BLOCKS) {
        const int base = bx * 1024 + tid * 4;
#pragma unroll
        for (int q = 0; q < 4; ++q) {
            const int id = base + q;            // id = c*128 + k
            const int c = id >> 7, k = id & 127;
            const int dir = c >= GATES;
            const int j = c - dir * GATES;
            const float* W = dir ? Wb : Wf;
            WbT[id] = __float2bfloat16(W[k * GATES + j]);
        }
    } else if (bx < PREP_WT_BLOCKS + PREP_TAB_BLOCKS) {
        const int p = bx - PREP_WT_BLOCKS;
        const bool isPos = p < 53;
        const float* Erow = isPos ? (Ep + p * EMB) : (Ed + (size_t)(p - 53) * EMB);
        const int rowoff = isPos ? EMB : 2 * EMB;
        float* dst = isPos ? (Ppos + (size_t)p * NCOL) : (Pdep + (size_t)(p - 53) * NCOL);
        for (int c = tid; c < NCOL; c += 256) {
            const int dir = c >= GATES;
            const int j = c - dir * GATES;
            const float* W = dir ? Wb : Wf;
            float s = 0.f;
            for (int k = 0; k < EMB; ++k)
                s = fmaf(Erow[k], W[(size_t)(rowoff + k) * GATES + j], s);
            if (!isPos) s += (dir ? bb_[j] : bf_[j]);
            dst[c] = s;
        }
    } else {
        // ---- bf16 probe ----
        if (tid < 64) {
            for (int e = tid; e < 512; e += 64) {
                const int m = e >> 5, k = e & 31;
                Ap[e] = f2bf((float)((m * 3 + k * 5) % 7 - 3));
            }
            for (int e = tid; e < 512; e += 64) {
                const int k = e >> 4, n = e & 15;
                Bp[e] = f2bf((float)((k * 7 + n * 3) % 5 - 2));
            }
        }
        __syncthreads();
        if (tid < 64) {
            const int l = tid, mn = l & 15, grp = l >> 4;
            float ref[4];
#pragma unroll
            for (int i = 0; i < 4; ++i) {
                const int m = grp * 4 + i;
                float s = 0.f;
                for (int k = 0; k < 32; ++k)
                    s += bf2f(Ap[m * 32 + k]) * bf2f(Bp[k * 16 + mn]);
                ref[i] = s;
            }
            short8v a8, b8, a44, b44;
#pragma unroll
            for (int e = 0; e < 8; ++e) {
                const int k8 = grp * 8 + e;
                const int k44 = (e >> 2) * 16 + grp * 4 + (e & 3);
                a8[e]  = Ap[mn * 32 + k8];
                b8[e]  = Bp[k8 * 16 + mn];
                a44[e] = Ap[mn * 32 + k44];
                b44[e] = Bp[k44 * 16 + mn];
            }
            f32x4 z = {0.f, 0.f, 0.f, 0.f};
            f32x4 d8  = __builtin_amdgcn_mfma_f32_16x16x32_bf16(a8,  b8,  z, 0, 0, 0);
            f32x4 d44 = __builtin_amdgcn_mfma_f32_16x16x32_bf16(a44, b44, z, 0, 0, 0);
            const bool ok8  = (d8[0] == ref[0]) && (d8[1] == ref[1]) &&
                              (d8[2] == ref[2]) && (d8[3] == ref[3]);
            const unsigned long long m8 = __ballot(ok8);
            if (tid == 0) flag[0] = (m8 == ~0ULL) ? 0 : 1;
            (void)d44;
        }
        __syncthreads();
        // ---- f16 probe ----
        if (tid < 64) {
            for (int e = tid; e < 512; e += 64) {
                const int m = e >> 5, k = e & 31;
                Ap[e] = __builtin_bit_cast(short, (_Float16)(float)((m * 3 + k * 5) % 7 - 3));
            }
            for (int e = tid; e < 512; e += 64) {
                const int k = e >> 4, n = e & 15;
                Bp[e] = __builtin_bit_cast(short, (_Float16)(float)((k * 7 + n * 3) % 5 - 2));
            }
        }
        __syncthreads();
        if (tid < 64) {
            const int l = tid, mn = l & 15, grp = l >> 4;
            float ref[4];
#pragma unroll
            for (int i = 0; i < 4; ++i) {
                const int m = grp * 4 + i;
                float s = 0.f;
                for (int k = 0; k < 32; ++k)
                    s += (float)__builtin_bit_cast(_Float16, Ap[m * 32 + k]) *
                         (float)__builtin_bit_cast(_Float16, Bp[k * 16 + mn]);
                ref[i] = s;
            }
            half8 a8, b8;
#pragma unroll
            for (int e = 0; e < 8; ++e) {
                const int k8 = grp * 8 + e;
                a8[e] = __builtin_bit_cast(_Float16, Ap[mn * 32 + k8]);
                b8[e] = __builtin_bit_cast(_Float16, Bp[k8 * 16 + mn]);
            }
            f32x4 z = {0.f, 0.f, 0.f, 0.f};
            f32x4 d8 = __builtin_amdgcn_mfma_f32_16x16x32_f16(a8, b8, z, 0, 0, 0);
            const bool ok8 = (d8[0] == ref[0]) && (d8[1] == ref[1]) &&
                             (d8[2] == ref[2]) && (d8[3] == ref[3]);
            const unsigned long long m8 = __ballot(ok8);
            if (tid == 0) flag[1] = (m8 == ~0ULL) ? 0 : 1;
        }
    }
}

// ---------------------------------------------------------------------------
// embed_gemm: xw2[t][b][cperm]  cperm = dir*400 + unit*4 + gate
// ---------------------------------------------------------------------------
#define MT 64
#define NT 160

__global__ __launch_bounds__(256) void embed_gemm(
    const int* __restrict__ words, const int* __restrict__ pos, const int* __restrict__ dep,
    const float* __restrict__ Ew, const __hip_bfloat16* __restrict__ WbT,
    const float* __restrict__ Ppos, const float* __restrict__ Pdep,
    const int* __restrict__ flag, __hip_bfloat16* __restrict__ xw2)
{
    __shared__ __align__(16) short As[MT * 128];
    __shared__ __align__(16) short Bs[NT * 128];
    __shared__ int widx[MT], pidx[MT], didx[MT];

    const int tid = threadIdx.x;
    const int bx = blockIdx.x, by = blockIdx.y;
    const int r0 = bx * MT;
    const int t = r0 >> 8, b0 = r0 & 255;
    const int n0 = by * NT;

    if (tid < MT)             widx[tid]          = words[(size_t)(b0 + tid) * T_LEN + t];
    else if (tid < 2 * MT)    pidx[tid - MT]     = pos[(size_t)(b0 + tid - MT) * T_LEN + t];
    else if (tid < 3 * MT)    didx[tid - 2 * MT] = dep[(size_t)(b0 + tid - 2 * MT) * T_LEN + t];
    __syncthreads();

#pragma unroll
    for (int q = 0; q < 4; ++q) {
        const int ch = tid + q * 256;
        const int row = ch >> 4, c16 = ch & 15;
        const float* src = Ew + (size_t)widx[row] * EMB + c16 * 8;
        const float4 v0 = *reinterpret_cast<const float4*>(src);
        const float4 v1 = *reinterpret_cast<const float4*>(src + 4);
        short8v pk;
        pk[0] = f2bf(v0.x); pk[1] = f2bf(v0.y); pk[2] = f2bf(v0.z); pk[3] = f2bf(v0.w);
        pk[4] = f2bf(v1.x); pk[5] = f2bf(v1.y); pk[6] = f2bf(v1.z); pk[7] = f2bf(v1.w);
        *reinterpret_cast<short8v*>(&As[row * 128 + ((c16 ^ (row & 7)) << 3)]) = pk;
    }
#pragma unroll
    for (int q = 0; q < 10; ++q) {
        const int ch = tid + q * 256;
        const int col = ch >> 4, c16 = ch & 15;
        const short* src = reinterpret_cast<const short*>(WbT) + (size_t)(n0 + col) * 128 + c16 * 8;
        const short8v v = *reinterpret_cast<const short8v*>(src);
        *reinterpret_cast<short8v*>(&Bs[col * 128 + ((c16 ^ (col & 7)) << 3)]) = v;
    }
    __syncthreads();

    const int w = tid >> 6, l = tid & 63;
    const int lr = l & 15, lg = l >> 4;
    const int arow = w * 16 + lr;

    f32x4 acc[10];
#pragma unroll
    for (int ni = 0; ni < 10; ++ni) acc[ni] = f32x4{0.f, 0.f, 0.f, 0.f};

    const int lay = flag[0];

    if (lay == 0) {
#pragma unroll
        for (int kk = 0; kk < 4; ++kk) {
            const int c16 = kk * 4 + lg;
            const short8v a = *reinterpret_cast<const short8v*>(
                &As[arow * 128 + ((c16 ^ (arow & 7)) << 3)]);
#pragma unroll
            for (int ni = 0; ni < 10; ++ni) {
                const int col = ni * 16 + lr;
                const short8v bfr = *reinterpret_cast<const short8v*>(
                    &Bs[col * 128 + ((c16 ^ (col & 7)) << 3)]);
                acc[ni] = __builtin_amdgcn_mfma_f32_16x16x32_bf16(a, bfr, acc[ni], 0, 0, 0);
            }
        }
    } else {
#pragma unroll
        for (int kk = 0; kk < 4; ++kk) {
            const int ch16 = kk * 4 + (lg >> 1);
            const int inner = (lg & 1) * 4;
            const int alo_i = arow * 128 + ((ch16 ^ (arow & 7)) << 3) + inner;
            const int ahi_i = arow * 128 + (((ch16 + 2) ^ (arow & 7)) << 3) + inner;
            const short4v alo = *reinterpret_cast<const short4v*>(&As[alo_i]);
            const short4v ahi = *reinterpret_cast<const short4v*>(&As[ahi_i]);
            short8v a;
            a[0] = alo[0]; a[1] = alo[1]; a[2] = alo[2]; a[3] = alo[3];
            a[4] = ahi[0]; a[5] = ahi[1]; a[6] = ahi[2]; a[7] = ahi[3];
#pragma unroll
            for (int ni = 0; ni < 10; ++ni) {
                const int col = ni * 16 + lr;
                const int blo_i = col * 128 + ((ch16 ^ (col & 7)) << 3) + inner;
                const int bhi_i = col * 128 + (((ch16 + 2) ^ (col & 7)) << 3) + inner;
                const short4v blo = *reinterpret_cast<const short4v*>(&Bs[blo_i]);
                const short4v bhi = *reinterpret_cast<const short4v*>(&Bs[bhi_i]);
                short8v b;
                b[0] = blo[0]; b[1] = blo[1]; b[2] = blo[2]; b[3] = blo[3];
                b[4] = bhi[0]; b[5] = bhi[1]; b[6] = bhi[2]; b[7] = bhi[3];
                acc[ni] = __builtin_amdgcn_mfma_f32_16x16x32_bf16(a, b, acc[ni], 0, 0, 0);
            }
        }
    }

    // epilogue: add tables, store bf16 to xw2[t][b][cperm]
    const int rbase = w * 16 + lg * 4;
    int pix[4], dix[4];
#pragma unroll
    for (int i = 0; i < 4; ++i) { pix[i] = pidx[rbase + i]; dix[i] = didx[rbase + i]; }
    short* xs = reinterpret_cast<short*>(xw2);
#pragma unroll
    for (int ni = 0; ni < 10; ++ni) {
        const int c = n0 + ni * 16 + lr;
        const int dirg = c >= GATES;
        const int j = c - dirg * GATES;
        const int gate = j / UNITS, unit = j % UNITS;
        const int cperm = dirg * GATES + unit * 4 + gate;
#pragma unroll
        for (int i = 0; i < 4; ++i) {
            const float v = acc[ni][i]
                          + Ppos[(size_t)pix[i] * NCOL + c]
                          + Pdep[(size_t)dix[i] * NCOL + c];
            xs[((size_t)t * B_SZ + (b0 + rbase + i)) * NCOL + cperm] = f2bf(v);
        }
    }
}

// ---------------------------------------------------------------------------
// lstm_mfma v3: z stays in registers (swapped-operand MFMA), two chains per
// block pipelined so MFMA(X) overlaps gates(Y) in every barrier interval.
// A = U'^T (reg-resident f16 frags, cols permuted unit*4+gate, padded to 512),
// B = h planes (f16 LDS [row][k]), D: lane owns all 4 gates of one (row,unit).
// Grid: 16 blocks (8 tile-pairs x 2 dirs), 512 threads (8 waves x 4 tiles).
// ---------------------------------------------------------------------------
#define BAR() do { \
    asm volatile("s_waitcnt lgkmcnt(0)" ::: "memory"); \
    __builtin_amdgcn_sched_barrier(0); \
    __builtin_amdgcn_s_barrier(); \
    __builtin_amdgcn_sched_barrier(0); \
} while (0)

__global__ __launch_bounds__(512, 1) void lstm_mfma(
    const int* __restrict__ words,
    const __hip_bfloat16* __restrict__ xw2,
    const float* __restrict__ Uf, const float* __restrict__ Ub,
    const int* __restrict__ flag,
    float* __restrict__ h_f, float* __restrict__ h_b)
{
    const int bk = blockIdx.x;          // 16 blocks
    const int dirv = bk & 1;
    const int tp = bk >> 1;             // tile-pair 0..7
    const int b0A = tp * 32, b0B = tp * 32 + 16;
    const float* U = dirv ? Ub : Uf;
    float* hout = dirv ? h_b : h_f;
    const int coff = dirv * GATES;

    __shared__ _Float16 plA[16 * HROW], plB[16 * HROW];
    __shared__ unsigned char mA[T_LEN * 16], mB[T_LEN * 16];

    const int tid = threadIdx.x;
    const int w = tid >> 6, l = tid & 63, lr = l & 15, lg = l >> 4;
    const int lay = flag[1];

    for (int i = tid; i < 16 * HROW; i += 512) { plA[i] = (_Float16)0.f; plB[i] = (_Float16)0.f; }
    for (int i = tid; i < T_LEN * 16; i += 512) {
        const int row = i & 15, tt = i >> 4;
        mA[i] = (unsigned char)(words[(size_t)(b0A + row) * T_LEN + tt] != 0);
        mB[i] = (unsigned char)(words[(size_t)(b0B + row) * T_LEN + tt] != 0);
    }

    // A-frags of U'^T, register resident. A-side: lane's m = lr -> col=ntg*16+lr
    half8 uf[NTILE][4];
#pragma unroll
    for (int nt = 0; nt < NTILE; ++nt) {
        const int ntg = w * NTILE + nt;
        const int colA = ntg * 16 + lr;
        const int uA = colA >> 2, gA = colA & 3;
#pragma unroll
        for (int kk = 0; kk < 4; ++kk) {
#pragma unroll
            for (int e = 0; e < 8; ++e) {
                const int kl = lay ? ((e >> 2) * 16 + lg * 4 + (e & 3)) : (lg * 8 + e);
                const int k = kk * 32 + kl;
                const float v = (k < UNITS && uA < UNITS)
                              ? U[(size_t)k * GATES + gA * UNITS + uA] : 0.f;
                uf[nt][kk][e] = (_Float16)v;
            }
        }
    }

    // D-side ownership: lane holds gates 0-3 of unit ntg*4+lg for batch-row lr.
    int unitD[NTILE]; bool actD[NTILE]; int pco[NTILE];
#pragma unroll
    for (int nt = 0; nt < NTILE; ++nt) {
        const int ntg = w * NTILE + nt;
        unitD[nt] = ntg * 4 + lg;
        actD[nt] = unitD[nt] < UNITS;
        const int uc = actD[nt] ? unitD[nt] : (UNITS - 1);
        pco[nt] = coff + uc * 4;
    }

    float cqA[NTILE] = {0,0,0,0}, hqA[NTILE] = {0,0,0,0};
    float cqB[NTILE] = {0,0,0,0}, hqB[NTILE] = {0,0,0,0};

    __syncthreads();

    const int t0 = dirv ? (T_LEN - 1) : 0;
    const int dt = dirv ? -1 : 1;
    const short* xs = reinterpret_cast<const short*>(xw2);
    auto tc = [&](int s) { int t = t0 + dt * s; return t < 0 ? 0 : (t > T_LEN - 1 ? T_LEN - 1 : t); };

    uint2 pfA[NTILE], pfB[NTILE], pfA2[NTILE], pfB2[NTILE];
#pragma unroll
    for (int nt = 0; nt < NTILE; ++nt) {
        pfA[nt] = *reinterpret_cast<const uint2*>(xs + ((size_t)t0 * B_SZ + b0A + lr) * NCOL + pco[nt]);
        pfB[nt] = *reinterpret_cast<const uint2*>(xs + ((size_t)t0 * B_SZ + b0B + lr) * NCOL + pco[nt]);
    }

    f32x4 accA[NTILE], accB[NTILE];

    auto mfma_ph = [&](const _Float16* pl, f32x4 (&acc)[NTILE], uint2 (&pfc)[NTILE],
                       uint2 (&pfn)[NTILE], int bc, int tn) {
#pragma unroll
        for (int nt = 0; nt < NTILE; ++nt)
            pfn[nt] = *reinterpret_cast<const uint2*>(
                xs + ((size_t)tn * B_SZ + bc + lr) * NCOL + pco[nt]);
        half8 af[4];
        if (lay == 0) {
#pragma unroll
            for (int kk = 0; kk < 4; ++kk)
                af[kk] = *reinterpret_cast<const half8*>(&pl[lr * HROW + kk * 32 + lg * 8]);
        } else {
#pragma unroll
            for (int kk = 0; kk < 4; ++kk) {
                const half4 x0 = *reinterpret_cast<const half4*>(&pl[lr * HROW + kk * 32 + lg * 4]);
                const half4 x1 = *reinterpret_cast<const half4*>(&pl[lr * HROW + kk * 32 + 16 + lg * 4]);
                half8 tv;
                tv[0] = x0[0]; tv[1] = x0[1]; tv[2] = x0[2]; tv[3] = x0[3];
                tv[4] = x1[0]; tv[5] = x1[1]; tv[6] = x1[2]; tv[7] = x1[3];
                af[kk] = tv;
            }
        }
#pragma unroll
        for (int nt = 0; nt < NTILE; ++nt) {
            f32x4 a = {0.f, 0.f, 0.f, 0.f};
#pragma unroll
            for (int kk = 0; kk < 4; ++kk)
                a = __builtin_amdgcn_mfma_f32_16x16x32_f16(uf[nt][kk], af[kk], a, 0, 0, 0);
            a[0] += bf2f((short)(pfc[nt].x & 0xffff));
            a[1] += bf2f((short)(pfc[nt].x >> 16));
            a[2] += bf2f((short)(pfc[nt].y & 0xffff));
            a[3] += bf2f((short)(pfc[nt].y >> 16));
            acc[nt] = a;
        }
    };

    auto gate_ph = [&](f32x4 (&acc)[NTILE], float (&cq)[NTILE], float (&hq)[NTILE],
                       _Float16* pl, const unsigned char* msk, int bc, int t) {
        const bool m = msk[t * 16 + lr] != 0;
#pragma unroll
        for (int nt = 0; nt < NTILE; ++nt) {
            const float ig = fast_sigmoid(acc[nt][0]);
            const float fg = fast_sigmoid(acc[nt][1]);
            const float gg = fast_tanh(acc[nt][2]);
            const float og = fast_sigmoid(acc[nt][3]);
            const float cn = fg * cq[nt] + ig * gg;
            const float hn = og * fast_tanh(cn);
            const float h2 = m ? hn : hq[nt];
            cq[nt] = m ? cn : cq[nt];
            hq[nt] = h2;
            if (actD[nt]) {
                pl[lr * HROW + unitD[nt]] = (_Float16)h2;
                hout[((size_t)t * B_SZ + bc + lr) * UNITS + unitD[nt]] = h2;
            }
        }
    };

    // prologue: MFMA_A(0)
    mfma_ph(plA, accA, pfA, pfA2, b0A, tc(1));
    BAR();

    for (int s = 0; s < T_LEN; s += 2) {
        const int ta = t0 + dt * s;
        const int tb = t0 + dt * (s + 1);
        // ph1: MFMA_B(s) || gates_A(s)
        mfma_ph(plB, accB, pfB, pfB2, b0B, tc(s + 1));
        gate_ph(accA, cqA, hqA, plA, mA, b0A, ta);
        BAR();
        // ph2: MFMA_A(s+1) || gates_B(s)
        mfma_ph(plA, accA, pfA2, pfA, b0A, tc(s + 2));
        gate_ph(accB, cqB, hqB, plB, mB, b0B, ta);
        BAR();
        // ph3: MFMA_B(s+1) || gates_A(s+1)
        mfma_ph(plB, accB, pfB2, pfB, b0B, tc(s + 2));
        gate_ph(accA, cqA, hqA, plA, mA, b0A, tb);
        BAR();
        // ph4: MFMA_A(s+2) || gates_B(s+1)
        if (s + 2 < T_LEN) {
            mfma_ph(plA, accA, pfA, pfA2, b0A, tc(s + 3));
            gate_ph(accB, cqB, hqB, plB, mB, b0B, tb);
            BAR();
        }
    }
    // tail: gates_B(255)
    gate_ph(accB, cqB, hqB, plB, mB, b0B, t0 + dt * (T_LEN - 1));
}

// ---------------------------------------------------------------------------
// out_proj: out[b][t] = sigmoid(h_f . Wo[0:100] + h_b . Wo[100:200] + bo)
// ---------------------------------------------------------------------------
__global__ __launch_bounds__(256) void out_proj(
    const float* __restrict__ h_f, const float* __restrict__ h_b,
    const float* __restrict__ Wo, const float* __restrict__ bo,
    float* __restrict__ out)
{
    const int tid = threadIdx.x;
    const int g = tid >> 2, sub = tid & 3;
    const int r = blockIdx.x * 64 + g;      // r = t*256 + b
    const int t = r >> 8, b = r & 255;

    const float* hf = h_f + (size_t)r * UNITS;
    const float* hb = h_b + (size_t)r * UNITS;

    float s = 0.f;
    const int k0 = sub * 25;
#pragma unroll
    for (int k = 0; k < 25; ++k) s = fmaf(hf[k0 + k], Wo[k0 + k], s);
#pragma unroll
    for (int k = 0; k < 25; ++k) s = fmaf(hb[k0 + k], Wo[UNITS + k0 + k], s);

    s += __shfl_xor(s, 1);
    s += __shfl_xor(s, 2);

    if (sub == 0)
        out[(size_t)b * T_LEN + t] = 1.f / (1.f + __expf(-(s + bo[0])));
}

// ---------------------------------------------------------------------------
extern "C" void kernel_launch(void* const* d_in, const int* in_sizes, int n_in,
                              void* d_out, int out_size, void* d_ws, size_t ws_size,
                              hipStream_t stream)
{
    const int*   words = (const int*)d_in[0];
    const int*   pos   = (const int*)d_in[1];
    const int*   dep   = (const int*)d_in[2];
    const float* Ew    = (const float*)d_in[3];
    const float* Ep    = (const float*)d_in[4];
    const float* Ed    = (const float*)d_in[5];
    const float* Wf    = (const float*)d_in[6];
    const float* Uf    = (const float*)d_in[7];
    const float* bf_   = (const float*)d_in[8];
    const float* Wb    = (const float*)d_in[9];
    const float* Ub    = (const float*)d_in[10];
    const float* bb_   = (const float*)d_in[11];
    const float* Wo    = (const float*)d_in[12];
    const float* bo    = (const float*)d_in[13];
    float* out = (float*)d_out;

    auto alignup = [](size_t x) { return (x + 255) & ~(size_t)255; };
    char* p = (char*)d_ws;
    __hip_bfloat16* xw2 = (__hip_bfloat16*)p; p += alignup((size_t)T_LEN * B_SZ * NCOL * 2);
    float* h_f = (float*)p;                   p += alignup((size_t)T_LEN * B_SZ * UNITS * 4);
    float* h_b = (float*)p;                   p += alignup((size_t)T_LEN * B_SZ * UNITS * 4);
    __hip_bfloat16* WbT = (__hip_bfloat16*)p; p += alignup((size_t)NCOL * 128 * 2);
    float* Ppos = (float*)p;                  p += alignup((size_t)53 * NCOL * 4);
    float* Pdep = (float*)p;                  p += alignup((size_t)54 * NCOL * 4);
    int* flag = (int*)p;

    prep<<<dim3(PREP_WT_BLOCKS + PREP_TAB_BLOCKS + 1), 256, 0, stream>>>(
        Wf, Wb, bf_, bb_, Ep, Ed, WbT, Ppos, Pdep, flag);

    embed_gemm<<<dim3((T_LEN * B_SZ) / MT, NCOL / NT), 256, 0, stream>>>(
        words, pos, dep, Ew, WbT, Ppos, Pdep, flag, xw2);

    lstm_mfma<<<dim3(16), 512, 0, stream>>>(
        words, xw2, Uf, Ub, flag, h_f, h_b);

    out_proj<<<dim3((T_LEN * B_SZ) / 64), 256, 0, stream>>>(h_f, h_b, Wo, bo, out);
}